// Round 9
// baseline (178.941 us; speedup 1.0000x reference)
//
#include <hip/hip_runtime.h>

#define HH 64
#define WW 64
#define S  68          // padded LDS row stride (floats)
#define PH 66          // padded rows (1-px zero frame)
#define NLQ 10
#define NP  5          // channel pairs
#define NT  1024       // threads (16 waves = 4/SIMD)
#define NG  16         // row groups
#define NR  4          // rows per thread

typedef float f32x2 __attribute__((ext_vector_type(2)));

// One block per image (grid=256 = 1 block/CU). Thread t: column x=t&63, rows
// y0..y0+3 (16 row-groups).
//
// Residency war summary (R1..R15): 90 uniform weights + 80 q0 floats never fit
// the per-wave unified VGPR budget (128 at 4 waves/SIMD, allocator grants
// 52-116 arch) -> ACC demotion or worse. R15 (103us, VALUBusy 66%, VGPR=52):
// stream = 471 instr/wave/step vs ~280 ideal; ~200 = accvgpr reads + splat
// movs for the 90 weight-pair regs that don't fit.
//
// R16 (this): weights leave the vector file ENTIRELY. v_pk_fma_f32 (VOP3P)
// takes ONE scalar operand = 64-bit SGPR pair. 45 transition pairs = 90 SGPRs
// (separate file, ~102 cap, zero VGPR cost, barrier-immune, zero extra
// instructions per use). Enforced by construction: inline asm with "s"
// constraint - no allocator heuristic involved. R13's SGPR overflow was
// wq+wt both live (s_loads hoisted to entry); sched_barrier(0) between the
// q0 section and wt loads makes liveness disjoint (45 pairs max).
// K-loop arch demand: q0p 40 + win 18 + acc 10 + misc ~= 85 < 128 ->
// no demotion anywhere. Same fma order as R15 -> identical numerics.

__device__ __forceinline__ void pkfma(f32x2& acc, const f32x2& w, const f32x2& v) {
  // acc = w * v + acc   (packed fp32; w in SGPR pair - the one scalar operand)
  asm("v_pk_fma_f32 %0, %1, %2, %0 op_sel:[0,0,0] op_sel_hi:[1,1,1]"
      : "+v"(acc) : "s"(w), "v"(v));
}

__global__ __launch_bounds__(NT, 4)
void vin_fused(
    const float* __restrict__ X,    // [B,2,64,64]
    const float* __restrict__ Wh,   // [150,2,3,3]
    const float* __restrict__ bh,   // [150]
    const float* __restrict__ Wr,   // [150]
    const float* __restrict__ Wq,   // [10,1,3,3]
    const float* __restrict__ wtr,  // [10,1,3,3] transition
    const float* __restrict__ Wc,   // [4096]
    const float* __restrict__ bc,   // [1]
    float* __restrict__ out)        // [256 critic] ++ [256*40960 q]
{
  __shared__ float vb[2][PH * S];
  __shared__ float rb[PH * S];
  __shared__ float Wef[19];
  __shared__ float Wpart[152];
  __shared__ float red[NG];

  const int b  = blockIdx.x;
  const int t  = threadIdx.x;
  const int x  = t & 63;
  const int yg = t >> 6;          // 0..15
  const int y0 = yg * NR;
  const int base0 = y0 * S + x;   // top-left of 3x3 window for row y0 (padded)

  // ---- zero LDS (frames must be 0; interiors overwritten) ----
  {
    float* vbf = &vb[0][0];
    for (int i = t; i < 2 * PH * S; i += NT) vbf[i] = 0.f;
    for (int i = t; i < PH * S; i += NT) rb[i] = 0.f;
  }
  __syncthreads();

  // ---- stage X into vb interiors; collapse 150-ch conv to Wef[19] ----
  const float* Xb = X + (size_t)b * (2 * HH * WW);
  for (int i = t; i < HH * WW; i += NT) {
    const int yy = i >> 6, xx = i & 63;
    vb[0][(yy + 1) * S + xx + 1] = Xb[i];
    vb[1][(yy + 1) * S + xx + 1] = Xb[HH * WW + i];
  }
  if (t < 152) {                       // parallel collapse: 19 outputs x 8 parts
    const int i = t >> 3, part = t & 7;
    float s = 0.f;
    if (i < 18) {
      for (int c = part; c < 150; c += 8) s += Wr[c] * Wh[c * 18 + i];
    } else {
      for (int c = part; c < 150; c += 8) s += Wr[c] * bh[c];
    }
    Wpart[t] = s;
  }
  __syncthreads();
  if (t < 19) {
    float s = 0.f;
#pragma unroll
    for (int k = 0; k < 8; ++k) s += Wpart[t * 8 + k];
    Wef[t] = s;
  }
  __syncthreads();

  // ---- r = conv(X, Weff, pad=1) + beff -> rb ----
  {
    float We[19];
#pragma unroll
    for (int i = 0; i < 19; ++i) We[i] = Wef[i];
#pragma unroll
    for (int j = 0; j < NR; ++j) {
      const int tb = base0 + j * S;
      float s = We[18];
#pragma unroll
      for (int dy = 0; dy < 3; ++dy)
#pragma unroll
        for (int dx = 0; dx < 3; ++dx) {
          const int idx = tb + dy * S + dx;
          s = fmaf(vb[0][idx], We[dy * 3 + dx], s);
          s = fmaf(vb[1][idx], We[9 + dy * 3 + dx], s);
        }
      rb[tb + S + 1] = s;
    }
  }
  __syncthreads();

  // ---- q0 = conv(r, Wq, pad=1) -> q0p pairs; v_init = max_l q0 -> vb[0] ----
  f32x2 q0p[NR][NP];
  {
    f32x2 wqp[NP][9];   // SGPR pairs ("s" use below); dead after this section
#pragma unroll
    for (int p = 0; p < NP; ++p)
#pragma unroll
      for (int k = 0; k < 9; ++k)
        wqp[p][k] = (f32x2){ Wq[(2 * p) * 9 + k], Wq[(2 * p + 1) * 9 + k] };
#pragma unroll
    for (int j = 0; j < NR; ++j) {
      const int a = base0 + j * S;
      f32x2 acc[NP];
#pragma unroll
      for (int p = 0; p < NP; ++p) acc[p] = (f32x2){0.f, 0.f};
#pragma unroll
      for (int dy = 0; dy < 3; ++dy)
#pragma unroll
        for (int dx = 0; dx < 3; ++dx) {
          const int k = dy * 3 + dx;
          const float wv = rb[a + dy * S + dx];
          const f32x2 ws = { wv, wv };
#pragma unroll
          for (int p = 0; p < NP; ++p) pkfma(acc[p], wqp[p][k], ws);
        }
#pragma unroll
      for (int p = 0; p < NP; ++p) q0p[j][p] = acc[p];
      f32x2 m01 = __builtin_elementwise_max(acc[0], acc[1]);
      f32x2 m23 = __builtin_elementwise_max(acc[2], acc[3]);
      m01 = __builtin_elementwise_max(m01, m23);
      m01 = __builtin_elementwise_max(m01, acc[4]);
      vb[0][base0 + (j + 1) * S + 1] = fmaxf(m01.x, m01.y);
    }
  }
  __syncthreads();

  // Fence: keep wt s_loads BELOW the q0 section so wq/wt SGPR-pair liveness
  // is disjoint (45 pairs max at any time; R13's overflow was 90 live pairs).
  __builtin_amdgcn_sched_barrier(0);

  // ---- transition weight pairs -> SGPR pairs (live through K-loop) ----
  f32x2 wtp[NP][9];
#pragma unroll
  for (int p = 0; p < NP; ++p)
#pragma unroll
    for (int k = 0; k < 9; ++k)
      wtp[p][k] = (f32x2){ wtr[(2 * p) * 9 + k], wtr[(2 * p + 1) * 9 + k] };

  // ---- K-loop: q = q0 + conv(v, w); v = max_ch(q) ----
  auto step = [&](const float* __restrict__ vin, float* __restrict__ vout) {
    float win[NR + 2][3];
#pragma unroll
    for (int rr = 0; rr < NR + 2; ++rr) {
      const int a = base0 + rr * S;
      win[rr][0] = vin[a];
      win[rr][1] = vin[a + 1];
      win[rr][2] = vin[a + 2];
    }
#pragma unroll
    for (int j = 0; j < NR; ++j) {
      f32x2 acc[NP];
#pragma unroll
      for (int p = 0; p < NP; ++p) acc[p] = q0p[j][p];
#pragma unroll
      for (int dy = 0; dy < 3; ++dy)
#pragma unroll
        for (int dx = 0; dx < 3; ++dx) {
          const int k = dy * 3 + dx;
          const float wv = win[j + dy][dx];
          const f32x2 ws = { wv, wv };
#pragma unroll
          for (int p = 0; p < NP; ++p) pkfma(acc[p], wtp[p][k], ws);
        }
      f32x2 m01 = __builtin_elementwise_max(acc[0], acc[1]);
      f32x2 m23 = __builtin_elementwise_max(acc[2], acc[3]);
      m01 = __builtin_elementwise_max(m01, m23);
      m01 = __builtin_elementwise_max(m01, acc[4]);
      vout[base0 + (j + 1) * S + 1] = fmaxf(m01.x, m01.y);
    }
    __syncthreads();
  };

#pragma unroll 1
  for (int s2 = 0; s2 < 19; ++s2) { step(vb[0], vb[1]); step(vb[1], vb[0]); }
  step(vb[0], vb[1]);   // it = 38: reads vb[0], writes vb[1]

  // ---- final iteration (it=39): emit q + critic dot ----
  float wcv[NR];
#pragma unroll
  for (int j = 0; j < NR; ++j) wcv[j] = Wc[(y0 + j) * WW + x];

  float* qo = out + 256 + (size_t)b * (NLQ * HH * WW) + y0 * WW + x;
  float acc_c = 0.f;
  {
    const float* vin = vb[1];
    float win[NR + 2][3];
#pragma unroll
    for (int rr = 0; rr < NR + 2; ++rr) {
      const int a = base0 + rr * S;
      win[rr][0] = vin[a];
      win[rr][1] = vin[a + 1];
      win[rr][2] = vin[a + 2];
    }
#pragma unroll
    for (int j = 0; j < NR; ++j) {
      f32x2 acc[NP];
#pragma unroll
      for (int p = 0; p < NP; ++p) acc[p] = q0p[j][p];
#pragma unroll
      for (int dy = 0; dy < 3; ++dy)
#pragma unroll
        for (int dx = 0; dx < 3; ++dx) {
          const int k = dy * 3 + dx;
          const float wv = win[j + dy][dx];
          const f32x2 ws = { wv, wv };
#pragma unroll
          for (int p = 0; p < NP; ++p) pkfma(acc[p], wtp[p][k], ws);
        }
#pragma unroll
      for (int p = 0; p < NP; ++p) {
        qo[(2 * p)     * (HH * WW) + j * WW] = acc[p].x;
        qo[(2 * p + 1) * (HH * WW) + j * WW] = acc[p].y;
      }
      f32x2 m01 = __builtin_elementwise_max(acc[0], acc[1]);
      f32x2 m23 = __builtin_elementwise_max(acc[2], acc[3]);
      m01 = __builtin_elementwise_max(m01, m23);
      m01 = __builtin_elementwise_max(m01, acc[4]);
      acc_c = fmaf(fmaxf(m01.x, m01.y), wcv[j], acc_c);
    }
  }

  // ---- block-reduce critic ----
#pragma unroll
  for (int off = 32; off > 0; off >>= 1) acc_c += __shfl_down(acc_c, off);
  if (x == 0) red[yg] = acc_c;
  __syncthreads();
  if (t == 0) {
    float s = bc[0];
#pragma unroll
    for (int i = 0; i < NG; ++i) s += red[i];
    out[b] = s;
  }
}

extern "C" void kernel_launch(void* const* d_in, const int* in_sizes, int n_in,
                              void* d_out, int out_size, void* d_ws, size_t ws_size,
                              hipStream_t stream) {
  (void)n_in; (void)out_size; (void)d_ws; (void)ws_size;
  const float* X   = (const float*)d_in[0];
  const float* Wh  = (const float*)d_in[1];
  const float* bh  = (const float*)d_in[2];
  const float* Wr  = (const float*)d_in[3];
  const float* Wq  = (const float*)d_in[4];
  const float* wtr = (const float*)d_in[5];
  const float* Wc  = (const float*)d_in[6];
  const float* bc  = (const float*)d_in[7];
  float* out = (float*)d_out;

  const int B = in_sizes[0] / (2 * HH * WW);   // 256
  vin_fused<<<B, NT, 0, stream>>>(X, Wh, bh, Wr, Wq, wtr, Wc, bc, out);
}

// Round 10
// 169.277 us; speedup vs baseline: 1.0571x; 1.0571x over previous
//
#include <hip/hip_runtime.h>

#define HH 64
#define WW 64
#define S  104         // padded LDS row stride. 68 suffices; 104 pushes total
                       // LDS to 82368B > 80KB so only ONE block/CU fits ->
                       // compiler budgets 256 VGPRs/wave (2 waves/SIMD)
                       // instead of 128 (the 2-block budget that caused every
                       // ACC-demotion plateau R1-R16).
#define PH 66          // padded rows (1-px zero frame)
#define NLQ 10
#define NP  5          // channel pairs
#define NR 8           // rows per thread (512 threads = 8 waves = 2/SIMD)

typedef float f32x2 __attribute__((ext_vector_type(2)));

// One block per image (grid=256 = 1 block/CU). Thread t: column x=t&63, rows
// y0..y0+7.
//
// THE DIAGNOSIS (R15/R16 VGPR_Count=52 cracked it): the allocator budgets
// arch VGPRs for the occupancy the LDS footprint PERMITS, not the occupancy
// the grid achieves. 54.7KB LDS -> 2 blocks/CU fit -> budget 128 (512thr) or
// 64 (1024thr) -> grant 52-116 -> q0[80]+weights[90] demoted to ACC -> every
// use pays v_accvgpr_read (the 1.5-2x VALU bloat seen all session).
// Attribute overrides (num_vgpr, waves_per_eu), readfirstlane, readlane,
// "s"-constrained pk asm, dead LDS pads: all defeated. The ONE lever that
// can't be defeated: physically oversized (live) LDS. S=104 does that.
//
// R17 = R12's pk kernel + S=104. At 256-reg budget the whole working set
// (q0p 80 + wtp 90 + win 30 + acc 10 + misc) is arch-resident: the K-loop
// stream is ~520 instr/wave/step (360 pk_fma core), no demotion traffic.
__global__ __launch_bounds__(512)
__attribute__((amdgpu_waves_per_eu(2, 2)))
void vin_fused(
    const float* __restrict__ X,    // [B,2,64,64]
    const float* __restrict__ Wh,   // [150,2,3,3]
    const float* __restrict__ bh,   // [150]
    const float* __restrict__ Wr,   // [150]
    const float* __restrict__ Wq,   // [10,1,3,3]
    const float* __restrict__ wtr,  // [10,1,3,3] transition
    const float* __restrict__ Wc,   // [4096]
    const float* __restrict__ bc,   // [1]
    float* __restrict__ out)        // [256 critic] ++ [256*40960 q]
{
  __shared__ float vb[2][PH * S];
  __shared__ float rb[PH * S];
  __shared__ float Wef[19];
  __shared__ float Wpart[152];
  __shared__ float red[8];

  const int b  = blockIdx.x;
  const int t  = threadIdx.x;
  const int x  = t & 63;
  const int yg = t >> 6;
  const int y0 = yg * NR;
  const int base0 = y0 * S + x;   // top-left of 3x3 window for row y0 (padded)

  // ---- zero LDS (frames must be 0; interiors overwritten) ----
  {
    float* vbf = &vb[0][0];
    for (int i = t; i < 2 * PH * S; i += 512) vbf[i] = 0.f;
    for (int i = t; i < PH * S; i += 512) rb[i] = 0.f;
  }
  __syncthreads();

  // ---- stage X into vb interiors; collapse 150-ch conv to Wef[19] ----
  const float* Xb = X + (size_t)b * (2 * HH * WW);
  for (int i = t; i < HH * WW; i += 512) {
    const int yy = i >> 6, xx = i & 63;
    vb[0][(yy + 1) * S + xx + 1] = Xb[i];
    vb[1][(yy + 1) * S + xx + 1] = Xb[HH * WW + i];
  }
  if (t < 152) {                       // parallel collapse: 19 outputs x 8 parts
    const int i = t >> 3, part = t & 7;
    float s = 0.f;
    if (i < 18) {
      for (int c = part; c < 150; c += 8) s += Wr[c] * Wh[c * 18 + i];
    } else {
      for (int c = part; c < 150; c += 8) s += Wr[c] * bh[c];
    }
    Wpart[t] = s;
  }
  __syncthreads();
  if (t < 19) {
    float s = 0.f;
#pragma unroll
    for (int k = 0; k < 8; ++k) s += Wpart[t * 8 + k];
    Wef[t] = s;
  }
  __syncthreads();

  // ---- r = conv(X, Weff, pad=1) + beff -> rb ----
  {
    float We[19];
#pragma unroll
    for (int i = 0; i < 19; ++i) We[i] = Wef[i];
#pragma unroll
    for (int j = 0; j < NR; ++j) {
      const int tb = base0 + j * S;
      float s = We[18];
#pragma unroll
      for (int dy = 0; dy < 3; ++dy)
#pragma unroll
        for (int dx = 0; dx < 3; ++dx) {
          const int idx = tb + dy * S + dx;
          s = fmaf(vb[0][idx], We[dy * 3 + dx], s);
          s = fmaf(vb[1][idx], We[9 + dy * 3 + dx], s);
        }
      rb[tb + S + 1] = s;
    }
  }
  __syncthreads();

  // ---- q0 = conv(r, Wq, pad=1) -> q0p pairs; v_init = max_l q0 -> vb[0] ----
  f32x2 q0p[NR][NP];
  {
    f32x2 wqp[NP][9];   // dead after this section (frees 90 regs)
#pragma unroll
    for (int p = 0; p < NP; ++p)
#pragma unroll
      for (int k = 0; k < 9; ++k)
        wqp[p][k] = (f32x2){ Wq[(2 * p) * 9 + k], Wq[(2 * p + 1) * 9 + k] };
#pragma unroll
    for (int j = 0; j < NR; ++j) {
      const int a = base0 + j * S;
      f32x2 acc[NP];
#pragma unroll
      for (int p = 0; p < NP; ++p) acc[p] = (f32x2){0.f, 0.f};
#pragma unroll
      for (int dy = 0; dy < 3; ++dy)
#pragma unroll
        for (int dx = 0; dx < 3; ++dx) {
          const int k = dy * 3 + dx;
          const float wv = rb[a + dy * S + dx];
          const f32x2 ws = { wv, wv };
#pragma unroll
          for (int p = 0; p < NP; ++p)
            acc[p] = __builtin_elementwise_fma(wqp[p][k], ws, acc[p]);
        }
#pragma unroll
      for (int p = 0; p < NP; ++p) q0p[j][p] = acc[p];
      f32x2 m01 = __builtin_elementwise_max(acc[0], acc[1]);
      f32x2 m23 = __builtin_elementwise_max(acc[2], acc[3]);
      m01 = __builtin_elementwise_max(m01, m23);
      m01 = __builtin_elementwise_max(m01, acc[4]);
      vb[0][base0 + (j + 1) * S + 1] = fmaxf(m01.x, m01.y);
    }
  }
  __syncthreads();

  // ---- transition weight pairs (steady-state resident; fits 256 budget) ----
  f32x2 wtp[NP][9];
#pragma unroll
  for (int p = 0; p < NP; ++p)
#pragma unroll
    for (int k = 0; k < 9; ++k)
      wtp[p][k] = (f32x2){ wtr[(2 * p) * 9 + k], wtr[(2 * p + 1) * 9 + k] };

  // ---- K-loop: q = q0 + conv(v, w); v = max_ch(q) ----
  auto step = [&](const float* __restrict__ vin, float* __restrict__ vout) {
    float win[NR + 2][3];
#pragma unroll
    for (int rr = 0; rr < NR + 2; ++rr) {
      const int a = base0 + rr * S;
      win[rr][0] = vin[a];
      win[rr][1] = vin[a + 1];
      win[rr][2] = vin[a + 2];
    }
#pragma unroll
    for (int j = 0; j < NR; ++j) {
      f32x2 acc[NP];
#pragma unroll
      for (int p = 0; p < NP; ++p) acc[p] = q0p[j][p];
#pragma unroll
      for (int dy = 0; dy < 3; ++dy)
#pragma unroll
        for (int dx = 0; dx < 3; ++dx) {
          const int k = dy * 3 + dx;
          const float wv = win[j + dy][dx];
          const f32x2 ws = { wv, wv };
#pragma unroll
          for (int p = 0; p < NP; ++p)
            acc[p] = __builtin_elementwise_fma(wtp[p][k], ws, acc[p]);
        }
      f32x2 m01 = __builtin_elementwise_max(acc[0], acc[1]);
      f32x2 m23 = __builtin_elementwise_max(acc[2], acc[3]);
      m01 = __builtin_elementwise_max(m01, m23);
      m01 = __builtin_elementwise_max(m01, acc[4]);
      vout[base0 + (j + 1) * S + 1] = fmaxf(m01.x, m01.y);
    }
    __syncthreads();
  };

#pragma unroll 1
  for (int s2 = 0; s2 < 19; ++s2) { step(vb[0], vb[1]); step(vb[1], vb[0]); }
  step(vb[0], vb[1]);   // it = 38: reads vb[0], writes vb[1]

  // ---- final iteration (it=39): emit q + critic dot ----
  float wcv[NR];
#pragma unroll
  for (int j = 0; j < NR; ++j) wcv[j] = Wc[(y0 + j) * WW + x];

  float* qo = out + 256 + (size_t)b * (NLQ * HH * WW) + y0 * WW + x;
  float acc_c = 0.f;
  {
    const float* vin = vb[1];
    float win[NR + 2][3];
#pragma unroll
    for (int rr = 0; rr < NR + 2; ++rr) {
      const int a = base0 + rr * S;
      win[rr][0] = vin[a];
      win[rr][1] = vin[a + 1];
      win[rr][2] = vin[a + 2];
    }
#pragma unroll
    for (int j = 0; j < NR; ++j) {
      f32x2 acc[NP];
#pragma unroll
      for (int p = 0; p < NP; ++p) acc[p] = q0p[j][p];
#pragma unroll
      for (int dy = 0; dy < 3; ++dy)
#pragma unroll
        for (int dx = 0; dx < 3; ++dx) {
          const int k = dy * 3 + dx;
          const float wv = win[j + dy][dx];
          const f32x2 ws = { wv, wv };
#pragma unroll
          for (int p = 0; p < NP; ++p)
            acc[p] = __builtin_elementwise_fma(wtp[p][k], ws, acc[p]);
        }
#pragma unroll
      for (int p = 0; p < NP; ++p) {
        qo[(2 * p)     * (HH * WW) + j * WW] = acc[p].x;
        qo[(2 * p + 1) * (HH * WW) + j * WW] = acc[p].y;
      }
      f32x2 m01 = __builtin_elementwise_max(acc[0], acc[1]);
      f32x2 m23 = __builtin_elementwise_max(acc[2], acc[3]);
      m01 = __builtin_elementwise_max(m01, m23);
      m01 = __builtin_elementwise_max(m01, acc[4]);
      acc_c = fmaf(fmaxf(m01.x, m01.y), wcv[j], acc_c);
    }
  }

  // ---- block-reduce critic ----
#pragma unroll
  for (int off = 32; off > 0; off >>= 1) acc_c += __shfl_down(acc_c, off);
  if (x == 0) red[yg] = acc_c;
  __syncthreads();
  if (t == 0) {
    float s = bc[0];
#pragma unroll
    for (int i = 0; i < 8; ++i) s += red[i];
    out[b] = s;
  }
}

extern "C" void kernel_launch(void* const* d_in, const int* in_sizes, int n_in,
                              void* d_out, int out_size, void* d_ws, size_t ws_size,
                              hipStream_t stream) {
  (void)n_in; (void)out_size; (void)d_ws; (void)ws_size;
  const float* X   = (const float*)d_in[0];
  const float* Wh  = (const float*)d_in[1];
  const float* bh  = (const float*)d_in[2];
  const float* Wr  = (const float*)d_in[3];
  const float* Wq  = (const float*)d_in[4];
  const float* wtr = (const float*)d_in[5];
  const float* Wc  = (const float*)d_in[6];
  const float* bc  = (const float*)d_in[7];
  float* out = (float*)d_out;

  const int B = in_sizes[0] / (2 * HH * WW);   // 256
  vin_fused<<<B, 512, 0, stream>>>(X, Wh, bh, Wr, Wq, wtr, Wc, bc, out);
}

// Round 11
// 162.799 us; speedup vs baseline: 1.0992x; 1.0398x over previous
//
#include <hip/hip_runtime.h>

#define HH 64
#define WW 64
#define S  68          // padded LDS row stride (floats)
#define PH 66          // padded rows (1-px zero frame)
#define NLQ 10
#define NP  5          // channel pairs
#define NR 8           // rows per thread (512 threads = 8 waves = 2/SIMD)

typedef float f32x2 __attribute__((ext_vector_type(2)));

// One block per image (grid=256 = 1 block/CU). Thread t: column x=t&63, rows
// y0..y0+7.
//
// Session facts (R1-R17):
//  - Allocator grants 52-116 arch VGPRs regardless of LDS footprint (R17:
//    1 block/CU via 83KB LDS -> still 88), launch attrs, or asm constraints.
//    Excess long-lived state ALWAYS lands in ACC regs (or worse).
//  - Every forced-residency scheme failed: LDS staging (pipe-bound), per-step
//    global (barrier blocks hoisting), readfirstlane/readlane (SGPR cap,
//    serialization), "s"-pk asm (SGPR spill), scratch asm (814MB).
//  - pk variants (R12/R15/R17, 103-106us, VALUBusy ~60%): measured stream
//    ~880 instr/wave/step vs ~520 ideal. Gap == 360 == one ACC read per
//    pk_fma: j-outer structure re-reads all 45 weight pairs PER ROW.
//
// R18: stop fighting residency; fix the READ COUNT. p-OUTER / j-inner:
// each weight pair is read into an SSA temp once per step (45 reads max,
// wherever it lives) and reused across 8 rows. Simultaneous arch pressure
// drops to ~100 (win 30 + acc 16 + w 18 + mm 16 + misc), near the grant.
// q0p persistent: 40 single-use ACC reads/step, irreducible and cheap.
// Same per-channel tap order as R12 -> identical numerics (max reorder is
// exact).
__global__ __launch_bounds__(512)
__attribute__((amdgpu_waves_per_eu(2, 2)))
void vin_fused(
    const float* __restrict__ X,    // [B,2,64,64]
    const float* __restrict__ Wh,   // [150,2,3,3]
    const float* __restrict__ bh,   // [150]
    const float* __restrict__ Wr,   // [150]
    const float* __restrict__ Wq,   // [10,1,3,3]
    const float* __restrict__ wtr,  // [10,1,3,3] transition
    const float* __restrict__ Wc,   // [4096]
    const float* __restrict__ bc,   // [1]
    float* __restrict__ out)        // [256 critic] ++ [256*40960 q]
{
  __shared__ float vb[2][PH * S];
  __shared__ float rb[PH * S];
  __shared__ float Wef[19];
  __shared__ float Wpart[152];
  __shared__ float red[8];

  const int b  = blockIdx.x;
  const int t  = threadIdx.x;
  const int x  = t & 63;
  const int yg = t >> 6;
  const int y0 = yg * NR;
  const int base0 = y0 * S + x;   // top-left of 3x3 window for row y0 (padded)

  // ---- zero LDS (frames must be 0; interiors overwritten) ----
  {
    float* vbf = &vb[0][0];
    for (int i = t; i < 2 * PH * S; i += 512) vbf[i] = 0.f;
    for (int i = t; i < PH * S; i += 512) rb[i] = 0.f;
  }
  __syncthreads();

  // ---- stage X into vb interiors; collapse 150-ch conv to Wef[19] ----
  const float* Xb = X + (size_t)b * (2 * HH * WW);
  for (int i = t; i < HH * WW; i += 512) {
    const int yy = i >> 6, xx = i & 63;
    vb[0][(yy + 1) * S + xx + 1] = Xb[i];
    vb[1][(yy + 1) * S + xx + 1] = Xb[HH * WW + i];
  }
  if (t < 152) {                       // parallel collapse: 19 outputs x 8 parts
    const int i = t >> 3, part = t & 7;
    float s = 0.f;
    if (i < 18) {
      for (int c = part; c < 150; c += 8) s += Wr[c] * Wh[c * 18 + i];
    } else {
      for (int c = part; c < 150; c += 8) s += Wr[c] * bh[c];
    }
    Wpart[t] = s;
  }
  __syncthreads();
  if (t < 19) {
    float s = 0.f;
#pragma unroll
    for (int k = 0; k < 8; ++k) s += Wpart[t * 8 + k];
    Wef[t] = s;
  }
  __syncthreads();

  // ---- r = conv(X, Weff, pad=1) + beff -> rb ----
  {
    float We[19];
#pragma unroll
    for (int i = 0; i < 19; ++i) We[i] = Wef[i];
#pragma unroll
    for (int j = 0; j < NR; ++j) {
      const int tb = base0 + j * S;
      float s = We[18];
#pragma unroll
      for (int dy = 0; dy < 3; ++dy)
#pragma unroll
        for (int dx = 0; dx < 3; ++dx) {
          const int idx = tb + dy * S + dx;
          s = fmaf(vb[0][idx], We[dy * 3 + dx], s);
          s = fmaf(vb[1][idx], We[9 + dy * 3 + dx], s);
        }
      rb[tb + S + 1] = s;
    }
  }
  __syncthreads();

  // ---- q0 = conv(r, Wq, pad=1) -> q0p pairs; v_init = max_l q0 -> vb[0] ----
  // p-outer here too (keeps pre-loop pressure low; wqp dies after this).
  f32x2 q0p[NR][NP];
  {
    float win[NR + 2][3];
#pragma unroll
    for (int rr = 0; rr < NR + 2; ++rr) {
      const int a = base0 + rr * S;
      win[rr][0] = rb[a];
      win[rr][1] = rb[a + 1];
      win[rr][2] = rb[a + 2];
    }
    f32x2 mm[NR];
#pragma unroll
    for (int p = 0; p < NP; ++p) {
      f32x2 w[9];
#pragma unroll
      for (int k = 0; k < 9; ++k)
        w[k] = (f32x2){ Wq[(2 * p) * 9 + k], Wq[(2 * p + 1) * 9 + k] };
#pragma unroll
      for (int j = 0; j < NR; ++j) {
        f32x2 acc = (f32x2){0.f, 0.f};
#pragma unroll
        for (int dy = 0; dy < 3; ++dy)
#pragma unroll
          for (int dx = 0; dx < 3; ++dx) {
            const float wv = win[j + dy][dx];
            acc = __builtin_elementwise_fma(w[dy * 3 + dx], (f32x2){wv, wv}, acc);
          }
        q0p[j][p] = acc;
        mm[j] = (p == 0) ? acc : __builtin_elementwise_max(mm[j], acc);
      }
    }
#pragma unroll
    for (int j = 0; j < NR; ++j)
      vb[0][base0 + (j + 1) * S + 1] = fmaxf(mm[j].x, mm[j].y);
  }
  __syncthreads();

  // ---- transition weight pairs (persistent; read-once-per-step by design) ----
  f32x2 wtp[NP][9];
#pragma unroll
  for (int p = 0; p < NP; ++p)
#pragma unroll
    for (int k = 0; k < 9; ++k)
      wtp[p][k] = (f32x2){ wtr[(2 * p) * 9 + k], wtr[(2 * p + 1) * 9 + k] };

  // ---- K-loop: q = q0 + conv(v, w); v = max_ch(q) ----
  // p OUTER / j inner: w[9] SSA temps read once per step, used 8x each.
  auto step = [&](const float* __restrict__ vin, float* __restrict__ vout) {
    float win[NR + 2][3];
#pragma unroll
    for (int rr = 0; rr < NR + 2; ++rr) {
      const int a = base0 + rr * S;
      win[rr][0] = vin[a];
      win[rr][1] = vin[a + 1];
      win[rr][2] = vin[a + 2];
    }
    f32x2 mm[NR];
#pragma unroll
    for (int p = 0; p < NP; ++p) {
      f32x2 w[9];
#pragma unroll
      for (int k = 0; k < 9; ++k) w[k] = wtp[p][k];
#pragma unroll
      for (int j = 0; j < NR; ++j) {
        f32x2 acc = q0p[j][p];
#pragma unroll
        for (int dy = 0; dy < 3; ++dy)
#pragma unroll
          for (int dx = 0; dx < 3; ++dx) {
            const float wv = win[j + dy][dx];
            acc = __builtin_elementwise_fma(w[dy * 3 + dx], (f32x2){wv, wv}, acc);
          }
        mm[j] = (p == 0) ? acc : __builtin_elementwise_max(mm[j], acc);
      }
    }
#pragma unroll
    for (int j = 0; j < NR; ++j)
      vout[base0 + (j + 1) * S + 1] = fmaxf(mm[j].x, mm[j].y);
    __syncthreads();
  };

#pragma unroll 1
  for (int s2 = 0; s2 < 19; ++s2) { step(vb[0], vb[1]); step(vb[1], vb[0]); }
  step(vb[0], vb[1]);   // it = 38: reads vb[0], writes vb[1]

  // ---- final iteration (it=39): emit q + critic dot ----
  float wcv[NR];
#pragma unroll
  for (int j = 0; j < NR; ++j) wcv[j] = Wc[(y0 + j) * WW + x];

  float* qo = out + 256 + (size_t)b * (NLQ * HH * WW) + y0 * WW + x;
  float acc_c = 0.f;
  {
    const float* vin = vb[1];
    float win[NR + 2][3];
#pragma unroll
    for (int rr = 0; rr < NR + 2; ++rr) {
      const int a = base0 + rr * S;
      win[rr][0] = vin[a];
      win[rr][1] = vin[a + 1];
      win[rr][2] = vin[a + 2];
    }
    f32x2 mm[NR];
#pragma unroll
    for (int p = 0; p < NP; ++p) {
      f32x2 w[9];
#pragma unroll
      for (int k = 0; k < 9; ++k) w[k] = wtp[p][k];
#pragma unroll
      for (int j = 0; j < NR; ++j) {
        f32x2 acc = q0p[j][p];
#pragma unroll
        for (int dy = 0; dy < 3; ++dy)
#pragma unroll
          for (int dx = 0; dx < 3; ++dx) {
            const float wv = win[j + dy][dx];
            acc = __builtin_elementwise_fma(w[dy * 3 + dx], (f32x2){wv, wv}, acc);
          }
        qo[(2 * p)     * (HH * WW) + j * WW] = acc.x;
        qo[(2 * p + 1) * (HH * WW) + j * WW] = acc.y;
        mm[j] = (p == 0) ? acc : __builtin_elementwise_max(mm[j], acc);
      }
    }
#pragma unroll
    for (int j = 0; j < NR; ++j)
      acc_c = fmaf(fmaxf(mm[j].x, mm[j].y), wcv[j], acc_c);
  }

  // ---- block-reduce critic ----
#pragma unroll
  for (int off = 32; off > 0; off >>= 1) acc_c += __shfl_down(acc_c, off);
  if (x == 0) red[yg] = acc_c;
  __syncthreads();
  if (t == 0) {
    float s = bc[0];
#pragma unroll
    for (int i = 0; i < 8; ++i) s += red[i];
    out[b] = s;
  }
}

extern "C" void kernel_launch(void* const* d_in, const int* in_sizes, int n_in,
                              void* d_out, int out_size, void* d_ws, size_t ws_size,
                              hipStream_t stream) {
  (void)n_in; (void)out_size; (void)d_ws; (void)ws_size;
  const float* X   = (const float*)d_in[0];
  const float* Wh  = (const float*)d_in[1];
  const float* bh  = (const float*)d_in[2];
  const float* Wr  = (const float*)d_in[3];
  const float* Wq  = (const float*)d_in[4];
  const float* wtr = (const float*)d_in[5];
  const float* Wc  = (const float*)d_in[6];
  const float* bc  = (const float*)d_in[7];
  float* out = (float*)d_out;

  const int B = in_sizes[0] / (2 * HH * WW);   // 256
  vin_fused<<<B, 512, 0, stream>>>(X, Wh, bh, Wr, Wq, wtr, Wc, bc, out);
}